// Round 2
// baseline (1081.142 us; speedup 1.0000x reference)
//
#include <hip/hip_runtime.h>
#include <stdint.h>

typedef __bf16 bf16x8 __attribute__((ext_vector_type(8)));
typedef float  f32x4  __attribute__((ext_vector_type(4)));

#define N_JOINT 21
#define TB 4
#define REAL_ROWS 84               // 21*4
#define RPAD 96                    // 6 MFMA M-tiles
#define BATCH 16384
#define TILES 8                    // tiles per block
#define NBLK (BATCH / (TB * TILES))   // 512 blocks
#define ZSTRIDE 129                // odd stride: bank = (r+c)%32, ~2-way

__device__ __forceinline__ uint32_t swz(uint32_t byteoff, uint32_t row) {
  return byteoff ^ ((row & 7u) << 4);
}
__device__ __forceinline__ uint16_t f2b(float v) {
  __bf16 b = (__bf16)v;
  return __builtin_bit_cast(uint16_t, b);
}

// (L z)[r][c], z in LDS row stride S floats. 21-joint hand tree.
// L[n][n]=1-1/deg, L[n][m]=-1/deg for nbrs; deg=#nbr+1.
__device__ __forceinline__ float lmix(const float* zbp, int S, int r, int c) {
  int e = r / 21;
  int n = r - e * 21;
  const float* rowb = zbp + e * 21 * S + c;
  float zv = rowb[n * S];
  float s = zv;
  float invd;
  if (n == 0) {
    s += rowb[1 * S] + rowb[5 * S] + rowb[9 * S] + rowb[13 * S] + rowb[17 * S];
    invd = 1.f / 6.f;
  } else {
    int p = (n - 1) & 3;
    if (p == 3) { s += rowb[(n - 1) * S]; invd = 0.5f; }
    else {
      int left = (p == 0) ? 0 : (n - 1);
      s += rowb[left * S] + rowb[(n + 1) * S];
      invd = 1.f / 3.f;
    }
  }
  return zv - invd * s;
}

// ---------------- prep: fp32 weights -> bf16 frag-layout in ws ----------------
// wf1[256][256] (n = concat(k0,k1) x Cout, k contiguous), wf2[256][128], wf3[16][128]
__global__ void prep_weights(const float* __restrict__ W1, const float* __restrict__ W2,
                             const float* __restrict__ W3, uint16_t* __restrict__ ws) {
  uint16_t* wf1 = ws;
  uint16_t* wf2 = ws + 65536;
  uint16_t* wf3 = ws + 65536 + 32768;
  for (int i = blockIdx.x * blockDim.x + threadIdx.x; i < 100352;
       i += gridDim.x * blockDim.x) {
    if (i < 65536) {
      int n = i >> 8, k = i & 255;
      float v = (n < 128) ? W1[k * 128 + n] : W1[32768 + k * 128 + (n - 128)];
      wf1[i] = f2b(v);
    } else if (i < 98304) {
      int j = i - 65536; int n = j >> 7, k = j & 127;
      float v = (n < 128) ? W2[k * 128 + n] : W2[16384 + k * 128 + (n - 128)];
      wf2[j] = f2b(v);
    } else {
      int j = i - 98304; int n = j >> 7, k = j & 127;
      float v = 0.f;
      if (n < 3)      v = W3[k * 3 + n];
      else if (n < 6) v = W3[384 + k * 3 + (n - 3)];
      wf3[j] = f2b(v);
    }
  }
}

// ---------------- fused main: weights in regs, persistent tiles ----------------
__global__ __launch_bounds__(512, 2)
void cheb3_main(const float* __restrict__ xp,
                const uint16_t* __restrict__ wf1, const uint16_t* __restrict__ wf2,
                const uint16_t* __restrict__ wf3,
                const float* __restrict__ b1p, const float* __restrict__ b2p,
                const float* __restrict__ b3p, float* __restrict__ outp)
{
  __shared__ __align__(16) uint16_t sA[RPAD * 256];   // x bf16, swizzled (48 KB)
  __shared__ __align__(16) uint16_t sH[RPAD * 128];   // h bf16, swizzled (24 KB)
  __shared__ float zb[REAL_ROWS * ZSTRIDE];           // z fp32 (42.4 KB)

  const int tid  = threadIdx.x;
  const int wid  = tid >> 6;
  const int lane = tid & 63;
  const int l15  = lane & 15;
  const int lk   = lane >> 4;
  char* sAc = (char*)sA;
  char* sHc = (char*)sH;

  // persistent B-fragments (per-lane): wave owns u-col block [wid*16,+16) and
  // the matching z-col block (+128). 112 VGPRs.
  bf16x8 wB1[8][2], wB2[4][2], wB3[4];
  {
    const int nu = wid * 16 + l15;
    #pragma unroll
    for (int ch = 0; ch < 8; ++ch) {
      wB1[ch][0] = *(const bf16x8*)(wf1 + nu * 256 + ch * 32 + lk * 8);
      wB1[ch][1] = *(const bf16x8*)(wf1 + (nu + 128) * 256 + ch * 32 + lk * 8);
    }
    #pragma unroll
    for (int ch = 0; ch < 4; ++ch) {
      wB2[ch][0] = *(const bf16x8*)(wf2 + nu * 128 + ch * 32 + lk * 8);
      wB2[ch][1] = *(const bf16x8*)(wf2 + (nu + 128) * 128 + ch * 32 + lk * 8);
      wB3[ch]    = *(const bf16x8*)(wf3 + l15 * 128 + ch * 32 + lk * 8);
    }
  }
  const int   cu    = wid * 16 + l15;
  const float bias1 = b1p[cu];
  const float bias2 = b2p[cu];
  const float bias3 = (l15 < 3) ? b3p[l15] : 0.f;

  // zero pad rows 84..95 (written once, never touched again)
  {
    uint4 z16 = make_uint4(0, 0, 0, 0);
    for (int i = tid; i < (12 * 256) / 8; i += 512) {
      int f0 = i * 8, r = 84 + (f0 >> 8), c = f0 & 255;
      *(uint4*)(sAc + swz(r * 512 + c * 2, r)) = z16;
    }
    for (int i = tid; i < (12 * 128) / 8; i += 512) {
      int f0 = i * 8, r = 84 + (f0 >> 7), c = f0 & 127;
      *(uint4*)(sHc + swz(r * 256 + c * 2, r)) = z16;
    }
  }

  // stage tile 0 synchronously
  {
    const float* xg = xp + (size_t)(blockIdx.x * TILES) * (TB * N_JOINT * 256);
    #pragma unroll
    for (int j = 0; j < 6; ++j) {
      int i = tid + j * 512;
      if (i < 2688) {                       // 84 rows * 32 octs
        int r = i >> 5, c8 = (i & 31) * 8;
        float4 v0 = *(const float4*)(xg + r * 256 + c8);
        float4 v1 = *(const float4*)(xg + r * 256 + c8 + 4);
        bf16x8 o;
        o[0] = (__bf16)v0.x; o[1] = (__bf16)v0.y; o[2] = (__bf16)v0.z; o[3] = (__bf16)v0.w;
        o[4] = (__bf16)v1.x; o[5] = (__bf16)v1.y; o[6] = (__bf16)v1.z; o[7] = (__bf16)v1.w;
        *(bf16x8*)(sAc + swz(r * 512 + c8 * 2, r)) = o;
      }
    }
  }
  __syncthreads();

  const f32x4 zero4 = {0.f, 0.f, 0.f, 0.f};
  float4 pA[6], pB[6];                       // prefetch regs (octs 0..2 / 3..5)

  for (int t = 0; t < TILES; ++t) {
    const int gtile = blockIdx.x * TILES + t;
    const bool pf = (t + 1 < TILES);
    const float* xn = xp + (size_t)(gtile + 1) * (TB * N_JOINT * 256);

    // ---------------- LAYER 1: sA[96][256] @ wB1 ----------------
    f32x4 acc[6][2];
    #pragma unroll
    for (int mt = 0; mt < 6; ++mt) { acc[mt][0] = zero4; acc[mt][1] = zero4; }
    #pragma unroll
    for (int ch = 0; ch < 8; ++ch) {
      bf16x8 a[6];
      #pragma unroll
      for (int mt = 0; mt < 6; ++mt) {
        int r = mt * 16 + l15;
        a[mt] = *(const bf16x8*)(sAc + swz(r * 512 + ch * 64 + lk * 16, r));
      }
      #pragma unroll
      for (int nt = 0; nt < 2; ++nt)
        #pragma unroll
        for (int mt = 0; mt < 6; ++mt)
          acc[mt][nt] = __builtin_amdgcn_mfma_f32_16x16x32_bf16(a[mt], wB1[ch][nt], acc[mt][nt], 0, 0, 0);
    }

    // prefetch issue, group A (octs 0..2, always in range)
    if (pf) {
      #pragma unroll
      for (int j = 0; j < 3; ++j) {
        int i = tid + j * 512;
        int r = i >> 5, c8 = (i & 31) * 8;
        pA[2 * j]     = *(const float4*)(xn + r * 256 + c8);
        pA[2 * j + 1] = *(const float4*)(xn + r * 256 + c8 + 4);
      }
    }

    // mix1: z -> zb (all 8 waves)
    #pragma unroll
    for (int mt = 0; mt < 6; ++mt)
      #pragma unroll
      for (int rg = 0; rg < 4; ++rg) {
        int r = mt * 16 + lk * 4 + rg;
        if (r < REAL_ROWS) zb[r * ZSTRIDE + cu] = acc[mt][1][rg];
      }
    __syncthreads();                          // z visible; layer1 sA reads done

    if (pf) {                                 // write prefetched octs 0..2 (sA dead)
      #pragma unroll
      for (int j = 0; j < 3; ++j) {
        int i = tid + j * 512;
        int r = i >> 5, c8 = (i & 31) * 8;
        bf16x8 o;
        o[0] = (__bf16)pA[2*j].x; o[1] = (__bf16)pA[2*j].y; o[2] = (__bf16)pA[2*j].z; o[3] = (__bf16)pA[2*j].w;
        o[4] = (__bf16)pA[2*j+1].x; o[5] = (__bf16)pA[2*j+1].y; o[6] = (__bf16)pA[2*j+1].z; o[7] = (__bf16)pA[2*j+1].w;
        *(bf16x8*)(sAc + swz(r * 512 + c8 * 2, r)) = o;
      }
      #pragma unroll
      for (int j = 3; j < 6; ++j) {           // issue group B (octs 3..5)
        int i = tid + j * 512;
        if (i < 2688) {
          int r = i >> 5, c8 = (i & 31) * 8;
          pB[2 * (j-3)]     = *(const float4*)(xn + r * 256 + c8);
          pB[2 * (j-3) + 1] = *(const float4*)(xn + r * 256 + c8 + 4);
        }
      }
    }

    // mix1 compute: h1 = u + L z + b1, leaky -> sH
    #pragma unroll
    for (int mt = 0; mt < 6; ++mt)
      #pragma unroll
      for (int rg = 0; rg < 4; ++rg) {
        int r = mt * 16 + lk * 4 + rg;
        if (r < REAL_ROWS) {
          float h = acc[mt][0][rg] + lmix(zb, ZSTRIDE, r, cu) + bias1;
          h = (h > 0.f) ? h : 0.01f * h;
          *(uint16_t*)(sHc + swz(r * 256 + cu * 2, r)) = f2b(h);
        }
      }
    __syncthreads();                          // sH ready

    // ---------------- LAYER 2: sH[96][128] @ wB2 ----------------
    #pragma unroll
    for (int mt = 0; mt < 6; ++mt) { acc[mt][0] = zero4; acc[mt][1] = zero4; }
    #pragma unroll
    for (int ch = 0; ch < 4; ++ch) {
      bf16x8 a[6];
      #pragma unroll
      for (int mt = 0; mt < 6; ++mt) {
        int r = mt * 16 + l15;
        a[mt] = *(const bf16x8*)(sHc + swz(r * 256 + ch * 64 + lk * 16, r));
      }
      #pragma unroll
      for (int nt = 0; nt < 2; ++nt)
        #pragma unroll
        for (int mt = 0; mt < 6; ++mt)
          acc[mt][nt] = __builtin_amdgcn_mfma_f32_16x16x32_bf16(a[mt], wB2[ch][nt], acc[mt][nt], 0, 0, 0);
    }

    // mix2: z -> zb (WAR vs mix1 lmix reads: covered by pre-layer2 barrier)
    #pragma unroll
    for (int mt = 0; mt < 6; ++mt)
      #pragma unroll
      for (int rg = 0; rg < 4; ++rg) {
        int r = mt * 16 + lk * 4 + rg;
        if (r < REAL_ROWS) zb[r * ZSTRIDE + cu] = acc[mt][1][rg];
      }
    if (pf) {                                 // write prefetched octs 3..5
      #pragma unroll
      for (int j = 3; j < 6; ++j) {
        int i = tid + j * 512;
        if (i < 2688) {
          int r = i >> 5, c8 = (i & 31) * 8;
          bf16x8 o;
          o[0] = (__bf16)pB[2*(j-3)].x; o[1] = (__bf16)pB[2*(j-3)].y;
          o[2] = (__bf16)pB[2*(j-3)].z; o[3] = (__bf16)pB[2*(j-3)].w;
          o[4] = (__bf16)pB[2*(j-3)+1].x; o[5] = (__bf16)pB[2*(j-3)+1].y;
          o[6] = (__bf16)pB[2*(j-3)+1].z; o[7] = (__bf16)pB[2*(j-3)+1].w;
          *(bf16x8*)(sAc + swz(r * 512 + c8 * 2, r)) = o;
        }
      }
    }
    __syncthreads();                          // z2 visible; layer2 sH reads done

    // mix2 compute: h2 -> sH
    #pragma unroll
    for (int mt = 0; mt < 6; ++mt)
      #pragma unroll
      for (int rg = 0; rg < 4; ++rg) {
        int r = mt * 16 + lk * 4 + rg;
        if (r < REAL_ROWS) {
          float h = acc[mt][0][rg] + lmix(zb, ZSTRIDE, r, cu) + bias2;
          h = (h > 0.f) ? h : 0.01f * h;
          *(uint16_t*)(sHc + swz(r * 256 + cu * 2, r)) = f2b(h);
        }
      }
    __syncthreads();                          // h2 ready; mix2 zb reads done

    // ---------------- LAYER 3: sH[96][128] @ wB3 (n: u=0..2, z=3..5) ----------------
    f32x4 acc3 = zero4;
    if (wid < 6) {
      #pragma unroll
      for (int ch = 0; ch < 4; ++ch) {
        int r = wid * 16 + l15;
        bf16x8 a3 = *(const bf16x8*)(sHc + swz(r * 256 + ch * 64 + lk * 16, r));
        acc3 = __builtin_amdgcn_mfma_f32_16x16x32_bf16(a3, wB3[ch], acc3, 0, 0, 0);
      }
    }
    // z3 -> zb (stride 4)
    if (wid < 6 && l15 >= 3 && l15 < 6) {
      #pragma unroll
      for (int rg = 0; rg < 4; ++rg) {
        int r = wid * 16 + lk * 4 + rg;
        if (r < REAL_ROWS) zb[r * 4 + (l15 - 3)] = acc3[rg];
      }
    }
    __syncthreads();
    if (wid < 6 && l15 < 3) {
      #pragma unroll
      for (int rg = 0; rg < 4; ++rg) {
        int r = wid * 16 + lk * 4 + rg;
        if (r < REAL_ROWS) {
          float v = acc3[rg] + lmix(zb, 4, r, l15) + bias3;
          int e = r / 21;
          int n = r - e * 21;
          outp[((size_t)(gtile * TB + e) * N_JOINT + n) * 3 + l15] = v;
        }
      }
    }
    __syncthreads();   // zb/sH safe for next tile's writes; sA writes drained
  }
}

extern "C" void kernel_launch(void* const* d_in, const int* in_sizes, int n_in,
                              void* d_out, int out_size, void* d_ws, size_t ws_size,
                              hipStream_t stream) {
  const float* xp  = (const float*)d_in[0];
  const float* W1p = (const float*)d_in[1];
  const float* b1p = (const float*)d_in[2];
  const float* W2p = (const float*)d_in[3];
  const float* b2p = (const float*)d_in[4];
  const float* W3p = (const float*)d_in[5];
  const float* b3p = (const float*)d_in[6];
  uint16_t* ws = (uint16_t*)d_ws;

  hipLaunchKernelGGL(prep_weights, dim3(196), dim3(512), 0, stream, W1p, W2p, W3p, ws);

  const uint16_t* wf1 = ws;
  const uint16_t* wf2 = ws + 65536;
  const uint16_t* wf3 = ws + 65536 + 32768;
  hipLaunchKernelGGL(cheb3_main, dim3(NBLK), dim3(512), 0, stream,
                     xp, wf1, wf2, wf3, b1p, b2p, b3p, (float*)d_out);
}